// Round 2
// baseline (225.302 us; speedup 1.0000x reference)
//
#include <hip/hip_runtime.h>
#include <hip/hip_bf16.h>

typedef __attribute__((ext_vector_type(8))) short short8_t;
typedef __attribute__((ext_vector_type(4))) float f32x4;

#define BATCH 16
#define CIN   512
#define COUT  512
#define TT    4096

__device__ __forceinline__ ushort f2bf(float f) {
    __hip_bfloat16 h = __float2bfloat16(f);   // RNE; compiler pairs into v_cvt_pk_bf16_f32
    return __builtin_bit_cast(ushort, h);
}

// LDS layout (per tile): k-major granules of 8 ushort (16B).
//   LA[kkq][ m ^ (kkq&7) ][8k]      kkq = kk>>3, plane = 1024 ushorts
//   LB[kkq][ n ^ ((n>>3)&7) ][8k]
// Fragment read = ds_read_b128 of 8 contiguous k per lane; XOR perm spreads banks.
// B writes: u32 (k,k+1 pair) at bank (n' mod 8)*4 + (kk&7)/2 -> 32 banks, 2-way (free).

extern "C" __global__ __launch_bounds__(256, 4)
void conv2x1_gemm(const float* __restrict__ pre, const float* __restrict__ W,
                  const float* __restrict__ bias, float* __restrict__ out)
{
    __shared__ ushort LA[8 * 1024];   // 16 KiB: 128 m x 64 k bf16
    __shared__ ushort LB[8 * 1024];   // 16 KiB: 64 k x 128 n bf16

    const int tid  = threadIdx.x;
    const int lane = tid & 63;
    const int wv   = tid >> 6;
    const int wm   = wv >> 1, wn = wv & 1;
    const int g    = lane >> 4;
    const int l15  = lane & 15;

    // XCD-chunked swizzle: consecutive ids (sharing a B-panel across 4 m-tiles)
    // land on the same XCD's L2.
    const int id   = ((blockIdx.x & 7) << 8) | (blockIdx.x >> 3);
    const int mblk = id & 3;
    const int ti   = (id >> 2) & 31;
    const int bb   = id >> 7;

    const int m0 = mblk << 7;
    const int t0 = ti << 7;

    const float* preB = pre + (size_t)bb * ((size_t)CIN * TT);

    // A staging coords (per-thread constants)
    const int a_m  = tid >> 4;   // + it*16 ; A: 8 iters of dwordx4 (4 k each)
    const int a_kq = tid & 15;

    // B staging coords: per it (= kkq), lane covers 2k x 2t block.
    const int b_tt = wv * 32 + (lane & 15) * 2;   // t within tile [0,128)
    const int b_kk = (lane >> 4) * 2;             // + it*8 ; k-pair within kkq-plane

    uint a_pk[8][2];
    uint b_pk[8][2];

    f32x4 acc[4][4];
#pragma unroll
    for (int i = 0; i < 4; ++i)
#pragma unroll
        for (int j = 0; j < 4; ++j) acc[i][j] = (f32x4)0.0f;

#define LOAD_A(KT) do { \
    _Pragma("unroll") \
    for (int it = 0; it < 8; ++it) { \
        const float4 v = *(const float4*)(W + (size_t)(m0 + it*16 + a_m) * CIN + (KT)*64 + a_kq*4); \
        a_pk[it][0] = (uint)f2bf(v.x) | ((uint)f2bf(v.y) << 16); \
        a_pk[it][1] = (uint)f2bf(v.z) | ((uint)f2bf(v.w) << 16); \
    } } while (0)

#define LOAD_B(KT) do { \
    _Pragma("unroll") \
    for (int it = 0; it < 8; ++it) { \
        const int k = (KT)*64 + it*8 + b_kk; \
        const float2 v0 = *(const float2*)(preB + (size_t)k       * TT + t0 + b_tt); \
        const float2 v1 = *(const float2*)(preB + (size_t)(k + 1) * TT + t0 + b_tt); \
        b_pk[it][0] = (uint)f2bf(v0.x) | ((uint)f2bf(v1.x) << 16); \
        b_pk[it][1] = (uint)f2bf(v0.y) | ((uint)f2bf(v1.y) << 16); \
    } } while (0)

#define WRITE_A() do { \
    _Pragma("unroll") \
    for (int it = 0; it < 8; ++it) { \
        const int m   = it*16 + a_m; \
        const int kkq = a_kq >> 1; \
        const int k7  = (a_kq & 1) << 2; \
        const int idx = (kkq << 10) + ((m ^ (kkq & 7)) << 3) + k7; \
        *(uint2*)&LA[idx] = make_uint2(a_pk[it][0], a_pk[it][1]); \
    } } while (0)

#define WRITE_B() do { \
    _Pragma("unroll") \
    for (int it = 0; it < 8; ++it) { \
        const int k7 = b_kk & 7; \
        const int n0 = b_tt; \
        const int n1 = b_tt + 1; \
        *(uint*)&LB[(it << 10) + ((n0 ^ ((n0 >> 3) & 7)) << 3) + k7] = b_pk[it][0]; \
        *(uint*)&LB[(it << 10) + ((n1 ^ ((n1 >> 3) & 7)) << 3) + k7] = b_pk[it][1]; \
    } } while (0)

#define COMPUTE() do { \
    _Pragma("unroll") \
    for (int ks = 0; ks < 2; ++ks) { \
        const int kkq = ks*4 + g; \
        short8_t af[4], bfr[4]; \
        _Pragma("unroll") \
        for (int mi = 0; mi < 4; ++mi) { \
            const int m = wm*64 + mi*16 + l15; \
            af[mi] = *(const short8_t*)&LA[(kkq << 10) + ((m ^ (kkq & 7)) << 3)]; \
        } \
        _Pragma("unroll") \
        for (int ni = 0; ni < 4; ++ni) { \
            const int n = wn*64 + ni*16 + l15; \
            bfr[ni] = *(const short8_t*)&LB[(kkq << 10) + ((n ^ ((n >> 3) & 7)) << 3)]; \
        } \
        _Pragma("unroll") \
        for (int mi = 0; mi < 4; ++mi) \
            _Pragma("unroll") \
            for (int ni = 0; ni < 4; ++ni) \
                acc[mi][ni] = __builtin_amdgcn_mfma_f32_16x16x32_bf16(af[mi], bfr[ni], acc[mi][ni], 0, 0, 0); \
    } } while (0)

    LOAD_A(0);
    LOAD_B(0);

    for (int kt = 0; kt < 8; ++kt) {
        __syncthreads();            // previous iteration's LDS reads complete
        WRITE_A();
        WRITE_B();
        __syncthreads();            // tile visible
        if (kt < 7) {               // issue next-tile global loads early (hide under MFMA)
            LOAD_A(kt + 1);
            LOAD_B(kt + 1);
        }
        COMPUTE();
    }

    // epilogue: out = 2*(acc + bias)
    const int orow = m0 + wm*64 + g*4;     // + mi*16 + r
    float bv[4][4];
#pragma unroll
    for (int mi = 0; mi < 4; ++mi)
#pragma unroll
        for (int r = 0; r < 4; ++r)
            bv[mi][r] = bias[orow + mi*16 + r];

    float* outB = out + (size_t)bb * ((size_t)COUT * TT);
#pragma unroll
    for (int mi = 0; mi < 4; ++mi) {
#pragma unroll
        for (int ni = 0; ni < 4; ++ni) {
            const int t = t0 + wn*64 + ni*16 + l15;
#pragma unroll
            for (int r = 0; r < 4; ++r) {
                const int o = orow + mi*16 + r;
                outB[(size_t)o * TT + t] = 2.0f * (acc[mi][ni][r] + bv[mi][r]);
            }
        }
    }
}

extern "C" void kernel_launch(void* const* d_in, const int* in_sizes, int n_in,
                              void* d_out, int out_size, void* d_ws, size_t ws_size,
                              hipStream_t stream)
{
    const float* pre  = (const float*)d_in[0];   // [16, 512, 4096] fp32
    const float* Wp   = (const float*)d_in[1];   // [512, 512] fp32
    const float* bias = (const float*)d_in[2];   // [512] fp32
    float* out = (float*)d_out;                  // [16, 512, 4096] fp32

    dim3 grid(BATCH * 4 * 32);   // 16 batches x 4 m-tiles x 32 t-tiles = 2048
    dim3 block(256);
    hipLaunchKernelGGL(conv2x1_gemm, grid, block, 0, stream, pre, Wp, bias, out);
}

// Round 3
// 155.855 us; speedup vs baseline: 1.4456x; 1.4456x over previous
//
#include <hip/hip_runtime.h>
#include <hip/hip_bf16.h>

typedef __attribute__((ext_vector_type(8))) short short8_t;
typedef __attribute__((ext_vector_type(4))) float f32x4;

#define BATCH 16
#define CIN   512
#define COUT  512
#define TT    4096

__device__ __forceinline__ ushort f2bf(float f) {
    __hip_bfloat16 h = __float2bfloat16(f);   // RNE
    return __builtin_bit_cast(ushort, h);
}

// 128x128 tile, BK=64, 8 waves (wave tile 32x64), LDS double-buffered,
// single barrier per K-step, B staged 2-deep in regs, A (L2-resident W) 1-deep.
// LDS layout: k-major granules of 8 ushort:
//   LA[kkq][ m ^ (kkq&7) ][8k]        plane = 1024 ushorts
//   LB[kkq][ n ^ ((n>>3)&7) ][8k]
// B writes are u32 k-pairs at bank (n'&7)*4 + k7/2 -> 2-way (free, verified R2).

extern "C" __global__ __launch_bounds__(512, 4)
void conv2x1_gemm(const float* __restrict__ pre, const float* __restrict__ W,
                  const float* __restrict__ bias, float* __restrict__ out)
{
    __shared__ ushort LA0[8192], LB0[8192], LA1[8192], LB1[8192];  // 4 x 16 KiB

    const int tid  = threadIdx.x;
    const int lane = tid & 63;
    const int wv   = tid >> 6;          // [0,8)
    const int wm   = wv >> 1;           // [0,4) : 32-row strip
    const int wn   = wv & 1;            // [0,2) : 64-col strip
    const int g    = lane >> 4;
    const int l15  = lane & 15;

    // XCD-chunked swizzle: 4 consecutive ids share a B-panel (same bb,ti).
    const int id   = ((blockIdx.x & 7) << 8) | (blockIdx.x >> 3);
    const int mblk = id & 3;
    const int ti   = (id >> 2) & 31;
    const int bb   = id >> 7;

    const int m0 = mblk << 7;
    const int t0 = ti << 7;

    const float* preB = pre + (size_t)bb * ((size_t)CIN * TT);

    // A staging: 4 iters of float4; m = it*32 + a_m, k-quad a_kq
    const int a_m  = tid >> 4;          // [0,32)
    const int a_kq = tid & 15;

    // B staging: per it (16k x 128t): lane covers 2k x 2t; wave covers 8k x 32t
    const int b_kk = ((lane >> 4) << 1) + ((wv & 1) << 3);   // [0,16) even
    const int b_tt = ((l15) << 1) + ((wv >> 1) << 5);        // [0,128) even

    uint apk[4][2];
    uint bpk0[4][2], bpk1[4][2];

    f32x4 acc[2][4];
#pragma unroll
    for (int i = 0; i < 2; ++i)
#pragma unroll
        for (int j = 0; j < 4; ++j) acc[i][j] = (f32x4)0.0f;

#define LOAD_A(KT) do { \
    _Pragma("unroll") \
    for (int it = 0; it < 4; ++it) { \
        const float4 v = *(const float4*)(W + (size_t)(m0 + it*32 + a_m) * CIN + (KT)*64 + a_kq*4); \
        apk[it][0] = (uint)f2bf(v.x) | ((uint)f2bf(v.y) << 16); \
        apk[it][1] = (uint)f2bf(v.z) | ((uint)f2bf(v.w) << 16); \
    } } while (0)

#define LOAD_B(KT, BPK) do { \
    _Pragma("unroll") \
    for (int it = 0; it < 4; ++it) { \
        const int k = (KT)*64 + it*16 + b_kk; \
        const float2 v0 = *(const float2*)(preB + (size_t)k       * TT + t0 + b_tt); \
        const float2 v1 = *(const float2*)(preB + (size_t)(k + 1) * TT + t0 + b_tt); \
        BPK[it][0] = (uint)f2bf(v0.x) | ((uint)f2bf(v1.x) << 16); \
        BPK[it][1] = (uint)f2bf(v0.y) | ((uint)f2bf(v1.y) << 16); \
    } } while (0)

#define WRITE_A(LA) do { \
    _Pragma("unroll") \
    for (int it = 0; it < 4; ++it) { \
        const int m   = it*32 + a_m; \
        const int kkq = a_kq >> 1; \
        const int k7  = (a_kq & 1) << 2; \
        const int idx = (kkq << 10) + ((m ^ (kkq & 7)) << 3) + k7; \
        *(uint2*)&LA[idx] = make_uint2(apk[it][0], apk[it][1]); \
    } } while (0)

#define WRITE_B(LB, BPK) do { \
    _Pragma("unroll") \
    for (int it = 0; it < 4; ++it) { \
        const int kk  = it*16 + b_kk; \
        const int kkq = kk >> 3, k7 = kk & 7; \
        const int n0  = b_tt, n1 = b_tt + 1; \
        *(uint*)&LB[(kkq << 10) + ((n0 ^ ((n0 >> 3) & 7)) << 3) + k7] = BPK[it][0]; \
        *(uint*)&LB[(kkq << 10) + ((n1 ^ ((n1 >> 3) & 7)) << 3) + k7] = BPK[it][1]; \
    } } while (0)

#define COMPUTE(LA, LB) do { \
    _Pragma("unroll") \
    for (int ks = 0; ks < 2; ++ks) { \
        const int kkq = ks*4 + g; \
        short8_t af[2], bfr[4]; \
        _Pragma("unroll") \
        for (int mi = 0; mi < 2; ++mi) { \
            const int m = wm*32 + mi*16 + l15; \
            af[mi] = *(const short8_t*)&LA[(kkq << 10) + ((m ^ (kkq & 7)) << 3)]; \
        } \
        _Pragma("unroll") \
        for (int ni = 0; ni < 4; ++ni) { \
            const int n = wn*64 + ni*16 + l15; \
            bfr[ni] = *(const short8_t*)&LB[(kkq << 10) + ((n ^ ((n >> 3) & 7)) << 3)]; \
        } \
        _Pragma("unroll") \
        for (int mi = 0; mi < 2; ++mi) \
            _Pragma("unroll") \
            for (int ni = 0; ni < 4; ++ni) \
                acc[mi][ni] = __builtin_amdgcn_mfma_f32_16x16x32_bf16(af[mi], bfr[ni], acc[mi][ni], 0, 0, 0); \
    } } while (0)

    // -------- prologue: tile0 -> L0; tile1 staged in regs --------
    LOAD_B(0, bpk0);
    LOAD_B(1, bpk1);
    LOAD_A(0);
    WRITE_A(LA0);
    WRITE_B(LB0, bpk0);
    LOAD_A(1);
    __syncthreads();

    // -------- main loop: one barrier per K-step --------
    // tile j lives in L{j&1}; B staging reg for tile j is bpk{j&1}.
#pragma unroll
    for (int kt = 0; kt < 8; ++kt) {
        if ((kt & 1) == 0) {
            if (kt + 2 < 8) LOAD_B(kt + 2, bpk0);        // into freed bpk0
            if (kt + 1 < 8) {
                WRITE_B(LB1, bpk1);                      // tile kt+1
                WRITE_A(LA1);
                if (kt + 2 < 8) LOAD_A(kt + 2);          // refill apk
            }
            COMPUTE(LA0, LB0);
        } else {
            if (kt + 2 < 8) LOAD_B(kt + 2, bpk1);
            if (kt + 1 < 8) {
                WRITE_B(LB0, bpk0);
                WRITE_A(LA0);
                if (kt + 2 < 8) LOAD_A(kt + 2);
            }
            COMPUTE(LA1, LB1);
        }
        if (kt < 7) __syncthreads();
    }

    // -------- epilogue: out = 2*(acc + bias) --------
    const int orow = m0 + wm*32 + g*4;     // + mi*16 + r
    float bv[2][4];
#pragma unroll
    for (int mi = 0; mi < 2; ++mi)
#pragma unroll
        for (int r = 0; r < 4; ++r)
            bv[mi][r] = bias[orow + mi*16 + r];

    float* outB = out + (size_t)bb * ((size_t)COUT * TT);
#pragma unroll
    for (int mi = 0; mi < 2; ++mi) {
#pragma unroll
        for (int ni = 0; ni < 4; ++ni) {
            const int t = t0 + wn*64 + ni*16 + l15;
#pragma unroll
            for (int r = 0; r < 4; ++r) {
                const int o = orow + mi*16 + r;
                outB[(size_t)o * TT + t] = 2.0f * (acc[mi][ni][r] + bv[mi][r]);
            }
        }
    }
}

extern "C" void kernel_launch(void* const* d_in, const int* in_sizes, int n_in,
                              void* d_out, int out_size, void* d_ws, size_t ws_size,
                              hipStream_t stream)
{
    const float* pre  = (const float*)d_in[0];   // [16, 512, 4096] fp32
    const float* Wp   = (const float*)d_in[1];   // [512, 512] fp32
    const float* bias = (const float*)d_in[2];   // [512] fp32
    float* out = (float*)d_out;                  // [16, 512, 4096] fp32

    dim3 grid(BATCH * 4 * 32);   // 2048
    dim3 block(512);
    hipLaunchKernelGGL(conv2x1_gemm, grid, block, 0, stream, pre, Wp, bias, out);
}

// Round 4
// 113.316 us; speedup vs baseline: 1.9883x; 1.3754x over previous
//
#include <hip/hip_runtime.h>
#include <hip/hip_bf16.h>

typedef __attribute__((ext_vector_type(8))) short short8_t;
typedef __attribute__((ext_vector_type(4))) float f32x4;

#define BATCH 16
#define CIN   512
#define COUT  512
#define TT    4096
#define BK    32
#define NKT   (CIN / BK)   // 16 K-steps

// pack 2 f32 -> u32 of 2 bf16 (RNE); compiler emits v_cvt_pk_bf16_f32
__device__ __forceinline__ uint pk2(float a, float b) {
    ushort lo = __builtin_bit_cast(ushort, __float2bfloat16(a));
    ushort hi = __builtin_bit_cast(ushort, __float2bfloat16(b));
    return (uint)lo | ((uint)hi << 16);
}

// Tile 128m x 64n, BK=32. 4 waves, wave-tile 32x64 (acc = 32 regs).
// LDS k-major granules of 8 ushort (16B):
//   LA[buf][p][ m ^ p ][8k]            p = k>>3 (4 planes of 1024 ushorts)
//   LB[buf][p][ n ^ ((n>>3)&7) ][8k]   (4 planes of 512 ushorts)
// Staging holds RAW f32; cvt+pack happens at WRITE time (one step after the
// load issues) so the vmcnt wait lands after COMPUTE, not at the load site.

extern "C" __global__ __launch_bounds__(256)
void conv2x1_gemm(const float* __restrict__ pre, const float* __restrict__ W,
                  const float* __restrict__ bias, float* __restrict__ out)
{
    __shared__ ushort LA[2][4096];   // 2 x 8 KiB
    __shared__ ushort LB[2][2048];   // 2 x 4 KiB

    const int tid  = threadIdx.x;
    const int lane = tid & 63;
    const int wm   = tid >> 6;          // wave id = m-strip [0,4)
    const int g    = lane >> 4;
    const int l15  = lane & 15;

    // XCD-chunked bijective swizzle (4096 = 8 * 512); ids id..id+3 share a
    // B-panel (same bb, ti) and land on the same XCD's L2.
    const int id   = ((blockIdx.x & 7) << 9) | (blockIdx.x >> 3);
    const int mblk = id & 3;
    const int ti   = (id >> 2) & 63;
    const int bb   = id >> 8;

    const int m0 = mblk << 7;   // [0,512) step 128
    const int t0 = ti << 6;     // [0,4096) step 64

    const float* preB = pre + (size_t)bb * ((size_t)CIN * TT);

    // A staging: thread = 1 m-row x 16 k (4 float4). a_m in [0,128), a_h in {0,1}.
    const int a_m = tid >> 1;
    const int a_h = tid & 1;

    // B staging: thread = 4 t x 2 k (2 float4). kp in [0,16), tg in [0,16).
    const int b_kp = tid >> 4;
    const int b_tg = tid & 15;

    float4 av[4];                        // A raw, 1-deep
    float4 b0a, b0b, b1a, b1b;           // B raw, 2-deep

    f32x4 acc[2][4];
#pragma unroll
    for (int i = 0; i < 2; ++i)
#pragma unroll
        for (int j = 0; j < 4; ++j) acc[i][j] = (f32x4)0.0f;

#define LOAD_A(KT) do { \
    _Pragma("unroll") \
    for (int j = 0; j < 4; ++j) \
        av[j] = *(const float4*)(W + (size_t)(m0 + a_m) * CIN + (KT)*BK + a_h*16 + j*4); \
    } while (0)

#define LOAD_B(KT, BA, BB) do { \
    const int k = (KT)*BK + 2*b_kp; \
    BA = *(const float4*)(preB + (size_t)k       * TT + t0 + 4*b_tg); \
    BB = *(const float4*)(preB + (size_t)(k + 1) * TT + t0 + 4*b_tg); \
    } while (0)

#define WRITE_A(BUF) do { \
    _Pragma("unroll") \
    for (int pl = 0; pl < 2; ++pl) { \
        const int p = a_h*2 + pl; \
        uint4 q; \
        q.x = pk2(av[2*pl].x, av[2*pl].y); \
        q.y = pk2(av[2*pl].z, av[2*pl].w); \
        q.z = pk2(av[2*pl+1].x, av[2*pl+1].y); \
        q.w = pk2(av[2*pl+1].z, av[2*pl+1].w); \
        *(uint4*)&LA[BUF][(p << 10) + ((a_m ^ p) << 3)] = q; \
    } } while (0)

#define WRITE_B(BUF, BA, BB) do { \
    const int p  = b_kp >> 2; \
    const int pp = b_kp & 3; \
    uint* lb32 = (uint*)&LB[BUF][0]; \
    _Pragma("unroll") \
    for (int j = 0; j < 4; ++j) { \
        const int n  = 4*b_tg + j; \
        const int np = n ^ ((n >> 3) & 7); \
        lb32[(p << 8) + (np << 2) + pp] = pk2(((const float*)&BA)[j], ((const float*)&BB)[j]); \
    } } while (0)

#define COMPUTE(BUF) do { \
    short8_t af[2], bf[4]; \
    _Pragma("unroll") \
    for (int mi = 0; mi < 2; ++mi) { \
        const int m = wm*32 + mi*16 + l15; \
        af[mi] = *(const short8_t*)&LA[BUF][(g << 10) + ((m ^ g) << 3)]; \
    } \
    _Pragma("unroll") \
    for (int ni = 0; ni < 4; ++ni) { \
        const int n  = ni*16 + l15; \
        const int np = n ^ ((n >> 3) & 7); \
        bf[ni] = *(const short8_t*)&LB[BUF][(g << 9) + (np << 3)]; \
    } \
    _Pragma("unroll") \
    for (int mi = 0; mi < 2; ++mi) \
        _Pragma("unroll") \
        for (int ni = 0; ni < 4; ++ni) \
            acc[mi][ni] = __builtin_amdgcn_mfma_f32_16x16x32_bf16(af[mi], bf[ni], acc[mi][ni], 0, 0, 0); \
    } while (0)

    // -------- prologue: tile0 -> LDS[0]; tile1 loads in flight --------
    LOAD_A(0);
    LOAD_B(0, b0a, b0b);
    WRITE_A(0);
    WRITE_B(0, b0a, b0b);
    LOAD_B(1, b1a, b1b);
    LOAD_A(1);
    __syncthreads();

    // -------- main loop: one barrier per K-step --------
    // tile j lives in LDS[j&1]; B raw regs for tile j are b{j&1}a/b.
#pragma unroll
    for (int kt = 0; kt < NKT; ++kt) {
        if ((kt & 1) == 0) {
            if (kt + 2 < NKT) LOAD_B(kt + 2, b0a, b0b);   // bpk0 freed (tile kt written)
            COMPUTE(0);
            if (kt + 1 < NKT) {
                WRITE_B(1, b1a, b1b);                     // tile kt+1 (loaded a step ago)
                WRITE_A(1);
                if (kt + 2 < NKT) LOAD_A(kt + 2);
            }
        } else {
            if (kt + 2 < NKT) LOAD_B(kt + 2, b1a, b1b);
            COMPUTE(1);
            if (kt + 1 < NKT) {
                WRITE_B(0, b0a, b0b);
                WRITE_A(0);
                if (kt + 2 < NKT) LOAD_A(kt + 2);
            }
        }
        if (kt + 1 < NKT) __syncthreads();
    }

    // -------- epilogue: out = 2*(acc + bias) --------
    const int orow = m0 + wm*32 + g*4;     // + mi*16 + r
    float bv[2][4];
#pragma unroll
    for (int mi = 0; mi < 2; ++mi)
#pragma unroll
        for (int r = 0; r < 4; ++r)
            bv[mi][r] = bias[orow + mi*16 + r];

    float* outB = out + (size_t)bb * ((size_t)COUT * TT);
#pragma unroll
    for (int mi = 0; mi < 2; ++mi) {
#pragma unroll
        for (int ni = 0; ni < 4; ++ni) {
            const int t = t0 + ni*16 + l15;
#pragma unroll
            for (int r = 0; r < 4; ++r) {
                const int o = orow + mi*16 + r;
                outB[(size_t)o * TT + t] = 2.0f * (acc[mi][ni][r] + bv[mi][r]);
            }
        }
    }
}

extern "C" void kernel_launch(void* const* d_in, const int* in_sizes, int n_in,
                              void* d_out, int out_size, void* d_ws, size_t ws_size,
                              hipStream_t stream)
{
    const float* pre  = (const float*)d_in[0];   // [16, 512, 4096] fp32
    const float* Wp   = (const float*)d_in[1];   // [512, 512] fp32
    const float* bias = (const float*)d_in[2];   // [512] fp32
    float* out = (float*)d_out;                  // [16, 512, 4096] fp32

    dim3 grid(BATCH * 4 * 64);   // 16 b x 4 m-tiles x 64 t-tiles = 4096
    dim3 block(256);
    hipLaunchKernelGGL(conv2x1_gemm, grid, block, 0, stream, pre, Wp, bias, out);
}

// Round 5
// 77.959 us; speedup vs baseline: 2.8900x; 1.4535x over previous
//
#include <hip/hip_runtime.h>
#include <hip/hip_bf16.h>

typedef __attribute__((ext_vector_type(8))) short short8_t;
typedef __attribute__((ext_vector_type(4))) float f32x4;

#define BATCH 16
#define CIN   512
#define COUT  512
#define TT    4096
#define BK    128
#define NKT   (CIN / BK)   // 4 K-steps

// pack 2 f32 -> u32 of 2 bf16 (RNE); compiler emits v_cvt_pk_bf16_f32
__device__ __forceinline__ uint pk2(float a, float b) {
    ushort lo = __builtin_bit_cast(ushort, __float2bfloat16(a));
    ushort hi = __builtin_bit_cast(ushort, __float2bfloat16(b));
    return (uint)lo | ((uint)hi << 16);
}

// ---------------------------------------------------------------------------
// Pre-pass: convert W (fp32 [512][512]) to bf16 in MFMA-fragment order:
//   Wb[bm][ksg][g][r][8k]  (ushort), bm=m>>4, r=m&15, ksg=k>>5, g=(k>>3)&3
// One A fragment = one coalesced dwordx4 at
//   byte offset bm*16384 + ksg*1024 + g*256 + r*16.
// ---------------------------------------------------------------------------
extern "C" __global__ __launch_bounds__(256)
void wconv(const float* __restrict__ W, ushort* __restrict__ Wb)
{
    const int i  = blockIdx.x * 256 + threadIdx.x;   // [0, 65536)
    const int m  = i >> 7;
    const int k0 = (i & 127) * 4;
    const float4 v = *(const float4*)(W + (size_t)m * CIN + k0);
    const int bm = m >> 4, r = m & 15;
    const int ksg = k0 >> 5, g = (k0 >> 3) & 3, k7 = k0 & 7;
    uint2 q;
    q.x = pk2(v.x, v.y);
    q.y = pk2(v.z, v.w);
    *(uint2*)&Wb[(size_t)bm * 8192 + ksg * 512 + g * 128 + r * 8 + k7] = q;
}

// ---------------------------------------------------------------------------
// Main GEMM: tile 128m x 64n, BK=128 (4 K-steps), 4 waves (wave 32m x 64n).
// A: direct from global (fragment-ordered bf16 in d_ws, or inline-cvt fallback).
// B: LDS double-buffered, k-major granules LB[p][n'][8k], p=k>>3,
//    n' = n ^ ((n>>3)&7). Writes/reads are b128, exactly 8 lanes per 4-bank
//    group -> conflict-free.
// Schedule per step: {load A(t) ; issue B(t+1) ; COMPUTE(t) ; cvt+write B(t+1) ;
// barrier} -- nothing in flight at the barrier, so its vmcnt(0) drain is free.
// ---------------------------------------------------------------------------
template<bool WSB>
__global__ __launch_bounds__(256)
void conv2x1_gemm(const float* __restrict__ pre, const float* __restrict__ W,
                  const ushort* __restrict__ Wb,
                  const float* __restrict__ bias, float* __restrict__ out)
{
    __shared__ alignas(16) ushort LB[2][16 * 512];   // 2 x 16 KiB

    const int tid  = threadIdx.x;
    const int lane = tid & 63;
    const int wm   = tid >> 6;          // wave = m-strip [0,4)
    const int g    = lane >> 4;
    const int l15  = lane & 15;

    // XCD-chunked bijective swizzle (4096 = 8*512); ids id..id+3 share a
    // B-panel (same bb, ti) on one XCD's L2.
    const int id   = ((blockIdx.x & 7) << 9) | (blockIdx.x >> 3);
    const int mblk = id & 3;
    const int ti   = (id >> 2) & 63;
    const int bb   = id >> 8;

    const int m0 = mblk << 7;   // [0,512) step 128
    const int t0 = ti << 6;     // [0,4096) step 64

    const float* preB   = pre + (size_t)bb * ((size_t)CIN * TT);
    const int    bmBase = (m0 >> 4) + wm * 2;

    // B staging: thread covers 8k x 4t. p = plane (k-octet), k0 = p*8.
    const int b_p  = tid >> 4;          // [0,16)
    const int b_tg = tid & 15;          // t = 4*b_tg
    const int k0   = b_p << 3;

    float4   braw[8];      // raw f32 B rows k0..k0+7, 4 t each
    short8_t af[4][2];     // A fragments [ks][mi] for current step

    f32x4 acc[2][4];
#pragma unroll
    for (int i = 0; i < 2; ++i)
#pragma unroll
        for (int j = 0; j < 4; ++j) acc[i][j] = (f32x4)0.0f;

#define LOAD_A(KT) do { \
    if constexpr (WSB) { \
        _Pragma("unroll") \
        for (int ks = 0; ks < 4; ++ks) \
            _Pragma("unroll") \
            for (int mi = 0; mi < 2; ++mi) \
                af[ks][mi] = *(const short8_t*)(Wb + (size_t)(bmBase + mi) * 8192 \
                                                + ((KT)*4 + ks) * 512 + g * 128 + l15 * 8); \
    } else { \
        _Pragma("unroll") \
        for (int ks = 0; ks < 4; ++ks) \
            _Pragma("unroll") \
            for (int mi = 0; mi < 2; ++mi) { \
                const float* ab = W + (size_t)(m0 + wm*32 + mi*16 + l15) * CIN \
                                  + (KT)*BK + ks*32 + g*8; \
                const float4 u0 = *(const float4*)ab; \
                const float4 u1 = *(const float4*)(ab + 4); \
                uint4 qq; \
                qq.x = pk2(u0.x, u0.y); qq.y = pk2(u0.z, u0.w); \
                qq.z = pk2(u1.x, u1.y); qq.w = pk2(u1.z, u1.w); \
                af[ks][mi] = __builtin_bit_cast(short8_t, qq); \
            } \
    } } while (0)

#define LOAD_B(KT) do { \
    _Pragma("unroll") \
    for (int j = 0; j < 8; ++j) \
        braw[j] = *(const float4*)(preB + (size_t)((KT)*BK + k0 + j) * TT + t0 + 4*b_tg); \
    } while (0)

#define CVT_WRITE(BUF) do { \
    _Pragma("unroll") \
    for (int jt = 0; jt < 4; ++jt) { \
        uint4 q; \
        q.x = pk2(((const float*)&braw[0])[jt], ((const float*)&braw[1])[jt]); \
        q.y = pk2(((const float*)&braw[2])[jt], ((const float*)&braw[3])[jt]); \
        q.z = pk2(((const float*)&braw[4])[jt], ((const float*)&braw[5])[jt]); \
        q.w = pk2(((const float*)&braw[6])[jt], ((const float*)&braw[7])[jt]); \
        const int n  = 4*b_tg + jt; \
        const int np = n ^ ((n >> 3) & 7); \
        *(uint4*)&LB[BUF][b_p * 512 + np * 8] = q; \
    } } while (0)

#define COMPUTE(BUF) do { \
    _Pragma("unroll") \
    for (int ks = 0; ks < 4; ++ks) { \
        short8_t bf[4]; \
        _Pragma("unroll") \
        for (int ni = 0; ni < 4; ++ni) { \
            const int n  = ni*16 + l15; \
            const int np = n ^ ((n >> 3) & 7); \
            bf[ni] = *(const short8_t*)&LB[BUF][(ks*4 + g) * 512 + np * 8]; \
        } \
        _Pragma("unroll") \
        for (int mi = 0; mi < 2; ++mi) \
            _Pragma("unroll") \
            for (int ni = 0; ni < 4; ++ni) \
                acc[mi][ni] = __builtin_amdgcn_mfma_f32_16x16x32_bf16(af[ks][mi], bf[ni], acc[mi][ni], 0, 0, 0); \
    } } while (0)

    // -------- prologue: tile0 -> LDS[0] --------
    LOAD_B(0);
    CVT_WRITE(0);
    __syncthreads();                 // vmcnt already 0 (cvt consumed loads)

    // -------- main loop: 4 steps, one free barrier each --------
#pragma unroll
    for (int kt = 0; kt < NKT; ++kt) {
        LOAD_A(kt);                              // issued FIRST (older in vmcnt FIFO)
        if (kt + 1 < NKT) LOAD_B(kt + 1);        // issued after; stays in flight thru COMPUTE
        if (kt & 1) COMPUTE(1); else COMPUTE(0);
        if (kt + 1 < NKT) {
            if (kt & 1) CVT_WRITE(0); else CVT_WRITE(1);   // consumes B(t+1) loads
            __syncthreads();                               // nothing in flight: free drain
        }
    }

    // -------- epilogue: out = 2*(acc + bias) --------
    const int orow = m0 + wm*32 + g*4;     // + mi*16 + r
    float bv[2][4];
#pragma unroll
    for (int mi = 0; mi < 2; ++mi)
#pragma unroll
        for (int r = 0; r < 4; ++r)
            bv[mi][r] = bias[orow + mi*16 + r];

    float* outB = out + (size_t)bb * ((size_t)COUT * TT);
#pragma unroll
    for (int mi = 0; mi < 2; ++mi) {
#pragma unroll
        for (int ni = 0; ni < 4; ++ni) {
            const int t = t0 + ni*16 + l15;
#pragma unroll
            for (int r = 0; r < 4; ++r) {
                const int o = orow + mi*16 + r;
                outB[(size_t)o * TT + t] = 2.0f * (acc[mi][ni][r] + bv[mi][r]);
            }
        }
    }
}

extern "C" void kernel_launch(void* const* d_in, const int* in_sizes, int n_in,
                              void* d_out, int out_size, void* d_ws, size_t ws_size,
                              hipStream_t stream)
{
    const float* pre  = (const float*)d_in[0];   // [16, 512, 4096] fp32
    const float* Wp   = (const float*)d_in[1];   // [512, 512] fp32
    const float* bias = (const float*)d_in[2];   // [512] fp32
    float* out = (float*)d_out;                  // [16, 512, 4096] fp32

    const bool usews = (ws_size >= (size_t)(COUT * CIN * sizeof(ushort)));  // 512 KiB

    if (usews) {
        ushort* Wb = (ushort*)d_ws;
        hipLaunchKernelGGL(wconv, dim3(256), dim3(256), 0, stream, Wp, Wb);
        hipLaunchKernelGGL((conv2x1_gemm<true>), dim3(BATCH * 4 * 64), dim3(256), 0, stream,
                           pre, Wp, Wb, bias, out);
    } else {
        hipLaunchKernelGGL((conv2x1_gemm<false>), dim3(BATCH * 4 * 64), dim3(256), 0, stream,
                           pre, Wp, (const ushort*)nullptr, bias, out);
    }
}